// Round 3
// baseline (239.208 us; speedup 1.0000x reference)
//
#include <hip/hip_runtime.h>

// Sparsemax, last dim d=1024, 32768 rows, fp32. TWO rows per wave (ILP),
// 4 waves/block -> 8 rows/block. No __syncthreads (per-wave LDS regions).
//
// tau* in [max-1, max): only candidates z > max-1 (E[K]~14 for N(0,1))
// matter. Compact them one-per-lane into LDS (K<=64 fast path), then
// Newton iteration t' = (sum_{c>t} c - 1)/#{c>t}: monotone from below on
// convex piecewise-linear f, exact at the wave-uniform fixed point.

#define ROW_D 1024
#define NEG_PAD -3.0e38f

__device__ __forceinline__ void wsum4(float& a, float& b, float& c, float& d) {
#pragma unroll
    for (int off = 1; off < 64; off <<= 1) {
        a += __shfl_xor(a, off, 64);
        b += __shfl_xor(b, off, 64);
        c += __shfl_xor(c, off, 64);
        d += __shfl_xor(d, off, 64);
    }
}
__device__ __forceinline__ void wmax2(float& a, float& b) {
#pragma unroll
    for (int off = 1; off < 64; off <<= 1) {
        a = fmaxf(a, __shfl_xor(a, off, 64));
        b = fmaxf(b, __shfl_xor(b, off, 64));
    }
}
__device__ __forceinline__ float wsum1(float v) {
#pragma unroll
    for (int off = 1; off < 64; off <<= 1) v += __shfl_xor(v, off, 64);
    return v;
}

__device__ __forceinline__ float row_max16(const float4* v) {
    float m = fmaxf(fmaxf(v[0].x, v[0].y), fmaxf(v[0].z, v[0].w));
#pragma unroll
    for (int j = 1; j < 4; ++j)
        m = fmaxf(m, fmaxf(fmaxf(v[j].x, v[j].y), fmaxf(v[j].z, v[j].w)));
    return m;
}

// Slow exact fallback for K>64 (statistically never taken for this data).
__device__ __forceinline__ float full_bisect(const float4* v, float lo, float hi) {
    for (int it = 0; it < 24; ++it) {
        const float t = 0.5f * (lo + hi);
        float s = 0.0f;
#pragma unroll
        for (int j = 0; j < 4; ++j) {
            s += fmaxf(v[j].x - t, 0.0f) + fmaxf(v[j].y - t, 0.0f);
            s += fmaxf(v[j].z - t, 0.0f) + fmaxf(v[j].w - t, 0.0f);
        }
        s = wsum1(s);
        if (s >= 1.0f) lo = t; else hi = t;
    }
    float s = 0.0f, k = 0.0f;
#pragma unroll
    for (int j = 0; j < 4; ++j) {
        float e;
        e = v[j].x; if (e > lo) { s += e; k += 1.0f; }
        e = v[j].y; if (e > lo) { s += e; k += 1.0f; }
        e = v[j].z; if (e > lo) { s += e; k += 1.0f; }
        e = v[j].w; if (e > lo) { s += e; k += 1.0f; }
    }
    s = wsum1(s); k = wsum1(k);
    return fminf(fmaxf((s - 1.0f) / k, lo), hi);
}

__global__ __launch_bounds__(256) void sparsemax_kernel(
    const float* __restrict__ z, float* __restrict__ out, int nrows) {
    const int wslot = (int)(threadIdx.x >> 6);
    const int lane  = (int)(threadIdx.x & 63u);
    const int ra = (int)(blockIdx.x << 3) + (wslot << 1);   // rows ra, ra+1
    if (ra >= nrows) return;
    const int rb = (ra + 1 < nrows) ? ra + 1 : ra;

    __shared__ float cbuf[4][2][64];

    const float4* __restrict__ za =
        reinterpret_cast<const float4*>(z + (size_t)ra * ROW_D);
    const float4* __restrict__ zb =
        reinterpret_cast<const float4*>(z + (size_t)rb * ROW_D);

    // 8 loads in flight (both rows), coalesced.
    float4 va[4], vb[4];
#pragma unroll
    for (int j = 0; j < 4; ++j) va[j] = za[lane + 64 * j];
#pragma unroll
    for (int j = 0; j < 4; ++j) vb[j] = zb[lane + 64 * j];

    // Row maxes (interleaved reduce).
    float ma = row_max16(va), mb = row_max16(vb);
    wmax2(ma, mb);
    const float loa = ma - 1.0f, lob = mb - 1.0f;

    // Pad candidate slots, then ballot/mbcnt compaction (one slot per lane).
    cbuf[wslot][0][lane] = NEG_PAD;
    cbuf[wslot][1][lane] = NEG_PAD;
    int Ka = 0, Kb = 0;
#pragma unroll
    for (int j = 0; j < 4; ++j) {
        const float ea[4] = {va[j].x, va[j].y, va[j].z, va[j].w};
        const float eb[4] = {vb[j].x, vb[j].y, vb[j].z, vb[j].w};
#pragma unroll
        for (int c = 0; c < 4; ++c) {
            {
                const bool cand = ea[c] > loa;
                const unsigned long long b = __ballot(cand);
                const int pre = (int)__builtin_amdgcn_mbcnt_hi(
                    (unsigned)(b >> 32),
                    __builtin_amdgcn_mbcnt_lo((unsigned)b, 0u));
                const int pos = Ka + pre;
                if (cand && pos < 64) cbuf[wslot][0][pos] = ea[c];
                Ka += __popcll(b);
            }
            {
                const bool cand = eb[c] > lob;
                const unsigned long long b = __ballot(cand);
                const int pre = (int)__builtin_amdgcn_mbcnt_hi(
                    (unsigned)(b >> 32),
                    __builtin_amdgcn_mbcnt_lo((unsigned)b, 0u));
                const int pos = Kb + pre;
                if (cand && pos < 64) cbuf[wslot][1][pos] = eb[c];
                Kb += __popcll(b);
            }
        }
    }
    // Same-wave LDS write->read: compiler inserts lgkmcnt wait; no barrier.
    const float ca = cbuf[wslot][0][lane];
    const float cb = cbuf[wslot][1][lane];

    float ta, tb;
    if (Ka <= 64 && Kb <= 64) {
        // Newton: monotone from below, wave-uniform fixed-point exit.
        ta = loa; tb = lob;
        for (int it = 0; it < 16; ++it) {
            float sa = (ca > ta) ? ca : 0.0f, na = (ca > ta) ? 1.0f : 0.0f;
            float sb = (cb > tb) ? cb : 0.0f, nb = (cb > tb) ? 1.0f : 0.0f;
            wsum4(sa, na, sb, nb);
            const float ta2 = (sa - 1.0f) / na;   // na>=1: max elem always > t
            const float tb2 = (sb - 1.0f) / nb;
            const bool done = (ta2 == ta) && (tb2 == tb);
            ta = ta2; tb = tb2;
            if (done) break;                       // wave-uniform
        }
    } else {
        ta = full_bisect(va, loa, ma);
        tb = full_bisect(vb, lob, mb);
    }

    // Epilogue: p = relu(z - tau), both rows, coalesced float4 stores.
    float4* __restrict__ pa = reinterpret_cast<float4*>(out + (size_t)ra * ROW_D);
    float4* __restrict__ pb = reinterpret_cast<float4*>(out + (size_t)rb * ROW_D);
#pragma unroll
    for (int j = 0; j < 4; ++j) {
        float4 oa, ob;
        oa.x = fmaxf(va[j].x - ta, 0.0f); oa.y = fmaxf(va[j].y - ta, 0.0f);
        oa.z = fmaxf(va[j].z - ta, 0.0f); oa.w = fmaxf(va[j].w - ta, 0.0f);
        ob.x = fmaxf(vb[j].x - tb, 0.0f); ob.y = fmaxf(vb[j].y - tb, 0.0f);
        ob.z = fmaxf(vb[j].z - tb, 0.0f); ob.w = fmaxf(vb[j].w - tb, 0.0f);
        pa[lane + 64 * j] = oa;
        pb[lane + 64 * j] = ob;
    }
}

extern "C" void kernel_launch(void* const* d_in, const int* in_sizes, int n_in,
                              void* d_out, int out_size, void* d_ws, size_t ws_size,
                              hipStream_t stream) {
    const float* z = (const float*)d_in[0];
    float* out = (float*)d_out;
    const int n = in_sizes[0];        // 8*4096*1024
    const int nrows = n / ROW_D;      // 32768
    const int blocks = (nrows + 7) / 8;   // 8 rows per 256-thread block
    sparsemax_kernel<<<blocks, 256, 0, stream>>>(z, out, nrows);
}

// Round 4
// 229.092 us; speedup vs baseline: 1.0442x; 1.0442x over previous
//
#include <hip/hip_runtime.h>

// Sparsemax, last dim d=1024, 32768 rows, fp32. One wave per row, 16
// register-resident elements/lane. ZERO LDS/DS-pipe traffic: all wave
// reductions via DPP (row_shr + row_bcast) on the VALU pipe; counts via
// ballot+popcount on the SALU pipe. Newton iteration
//   t' = t + (sum(relu(z-t)) - 1)/#{z>t}
// from t0 = max-1 is monotone from below on the convex piecewise-linear
// objective and lands exactly on the root's linear segment (~4-6 iters).

#define ROW_D 1024

typedef float f4 __attribute__((ext_vector_type(4)));

template <int CTRL, int RMASK>
__device__ __forceinline__ float dpp_mv(float x) {
    return __builtin_bit_cast(float, __builtin_amdgcn_update_dpp(
        __builtin_bit_cast(int, x), __builtin_bit_cast(int, x),
        CTRL, RMASK, 0xf, false));
}

// Wave64 sum -> total lands in lane 63. row_shr:k folds each 16-lane row
// into its top lane (invalid-src lanes keep old=x; the doubling there
// never feeds the top-lane tree). bcast15/31 fold rows.
__device__ __forceinline__ float dpp_sum_to63(float x) {
    x += dpp_mv<0x111, 0xf>(x);   // row_shr:1
    x += dpp_mv<0x112, 0xf>(x);   // row_shr:2
    x += dpp_mv<0x114, 0xf>(x);   // row_shr:4
    x += dpp_mv<0x118, 0xf>(x);   // row_shr:8
    x += dpp_mv<0x142, 0xa>(x);   // row_bcast15 -> rows 1,3
    x += dpp_mv<0x143, 0xc>(x);   // row_bcast31 -> rows 2,3
    return x;
}
__device__ __forceinline__ float dpp_max_to63(float x) {
    x = fmaxf(x, dpp_mv<0x111, 0xf>(x));
    x = fmaxf(x, dpp_mv<0x112, 0xf>(x));
    x = fmaxf(x, dpp_mv<0x114, 0xf>(x));
    x = fmaxf(x, dpp_mv<0x118, 0xf>(x));
    x = fmaxf(x, dpp_mv<0x142, 0xa>(x));
    x = fmaxf(x, dpp_mv<0x143, 0xc>(x));
    return x;
}
__device__ __forceinline__ float bcast63(float x) {
    return __builtin_bit_cast(float,
        __builtin_amdgcn_readlane(__builtin_bit_cast(int, x), 63));
}

__global__ __launch_bounds__(256) void sparsemax_kernel(
    const float* __restrict__ z, float* __restrict__ out, int nrows) {
    const int lane = (int)(threadIdx.x & 63u);
    const int row  = (int)(blockIdx.x << 2) + (int)(threadIdx.x >> 6);
    if (row >= nrows) return;

    const f4* __restrict__ zin = reinterpret_cast<const f4*>(z + (size_t)row * ROW_D);
    f4* __restrict__ pout      = reinterpret_cast<f4*>(out + (size_t)row * ROW_D);

    // 16 elements/lane, 4 coalesced dwordx4 loads (1 KB/wave/inst).
    f4 v[4];
#pragma unroll
    for (int j = 0; j < 4; ++j) v[j] = zin[lane + 64 * j];

    // Row max: pairwise tree in registers, then DPP wave-max.
    float mj[4];
#pragma unroll
    for (int j = 0; j < 4; ++j)
        mj[j] = fmaxf(fmaxf(v[j].x, v[j].y), fmaxf(v[j].z, v[j].w));
    float m = fmaxf(fmaxf(mj[0], mj[1]), fmaxf(mj[2], mj[3]));
    m = bcast63(dpp_max_to63(m));

    // Newton from below; wave-uniform everything, no divergence.
    float t = m - 1.0f;
#pragma unroll 1
    for (int it = 0; it < 16; ++it) {
        float sj[4];
        int n = 0;
#pragma unroll
        for (int j = 0; j < 4; ++j) {
            const float d0 = v[j].x - t, d1 = v[j].y - t;
            const float d2 = v[j].z - t, d3 = v[j].w - t;
            sj[j] = (fmaxf(d0, 0.0f) + fmaxf(d1, 0.0f)) +
                    (fmaxf(d2, 0.0f) + fmaxf(d3, 0.0f));
            n += __popcll(__ballot(d0 > 0.0f));
            n += __popcll(__ballot(d1 > 0.0f));
            n += __popcll(__ballot(d2 > 0.0f));
            n += __popcll(__ballot(d3 > 0.0f));
        }
        float S = bcast63(dpp_sum_to63((sj[0] + sj[1]) + (sj[2] + sj[3])));
        // n >= 1 always (t < max). S(t) >= 1 while below the root.
        const float t2 = t + (S - 1.0f) / (float)n;
        if (t2 - t <= 1e-6f) { t = t2; break; }   // wave-uniform exit
        t = t2;
    }

    // p = relu(z - tau); nontemporal: output is never re-read, keep L3 for input.
#pragma unroll
    for (int j = 0; j < 4; ++j) {
        f4 o;
        o.x = fmaxf(v[j].x - t, 0.0f);
        o.y = fmaxf(v[j].y - t, 0.0f);
        o.z = fmaxf(v[j].z - t, 0.0f);
        o.w = fmaxf(v[j].w - t, 0.0f);
        __builtin_nontemporal_store(o, pout + lane + 64 * j);
    }
}

extern "C" void kernel_launch(void* const* d_in, const int* in_sizes, int n_in,
                              void* d_out, int out_size, void* d_ws, size_t ws_size,
                              hipStream_t stream) {
    const float* z = (const float*)d_in[0];
    float* out = (float*)d_out;
    const int n = in_sizes[0];        // 8*4096*1024
    const int nrows = n / ROW_D;      // 32768
    const int blocks = (nrows + 3) / 4;   // 4 rows (waves) per 256-thread block
    sparsemax_kernel<<<blocks, 256, 0, stream>>>(z, out, nrows);
}